// Round 16
// baseline (67.597 us; speedup 1.0000x reference)
//
#include <hip/hip_runtime.h>
#include <hip/hip_bf16.h>

#define F_FEAT 32
#define D_DIM 64
#define B_SZ 1024
#define EMB 2048
#define P_PAIRS 496
#define KPAD 512
#define OUT_N 512
#define OUT_STRIDE 2560
#define LN_EPS 1e-6f

typedef __attribute__((ext_vector_type(8))) short bf16x8;
typedef __attribute__((ext_vector_type(4))) float f32x4;

__device__ inline ushort f2bf(float f) {
    union { float f; unsigned u; } a; a.f = f;
    unsigned u = a.u;
    unsigned r = (u + 0x7FFFu + ((u >> 16) & 1u)) >> 16;   // RTNE
    return (ushort)r;
}
__device__ inline float bf2f(ushort u) {
    union { unsigned u; float f; } a; a.u = ((unsigned)u) << 16;
    return a.f;
}

// ---------- front (256 thr): senet 1-row/block | Wp | Wo | db pad ----------
// blocks [0,1024)      : SENet+LN, one batch row per block, register-resident
// blocks [1024,1520)   : Wp[p][d][e] -> Wpt[p][e][d] bf16 (R2-proven)
// blocks [1520,1584)   : Wo[k][n] -> Wot[n][k] bf16, k padded (R2-proven)
// blocks [1584,1592)   : zero db[:, 496:512]
__global__ __launch_bounds__(256) void k_front(
        const float* __restrict__ x, ushort* __restrict__ xb,
        const float* __restrict__ W1, const float* __restrict__ b1,
        const float* __restrict__ W2, const float* __restrict__ b2,
        const float* __restrict__ ln_s, const float* __restrict__ ln_b,
        const float* __restrict__ Wp, ushort* __restrict__ Wpt,
        const float* __restrict__ Wo, ushort* __restrict__ Wot,
        ushort* __restrict__ db, float* __restrict__ out) {
    __shared__ union {
        float tile[64][65];
        struct {
            float zs[128];
            float a1s[32];
            float mlpred[8][32];
            float red[2][4];
        } sn;
    } sm;
    int t = threadIdx.x;
    int blk = blockIdx.x;

    if (blk < 1024) {
        // ================ SENet, 1 row, register-resident ================
        int b = blk;
        int e0 = t * 8;
        const float* xrow = x + (size_t)b * EMB + e0;
        float4 v0 = *reinterpret_cast<const float4*>(xrow);
        float4 v1 = *reinterpret_cast<const float4*>(xrow + 4);
        float xr[8] = {v0.x, v0.y, v0.z, v0.w, v1.x, v1.y, v1.z, v1.w};

        // emit xb (16B per thread, coalesced)
        bf16x8 ob;
#pragma unroll
        for (int u = 0; u < 8; ++u) ob[u] = (short)f2bf(xr[u]);
        *reinterpret_cast<bf16x8*>(xb + (size_t)b * EMB + e0) = ob;

        // squeeze: thread owns 1/4 of one (f,gg) 32-elem window
        {
            float mx = xr[0], sum = xr[0];
#pragma unroll
            for (int u = 1; u < 8; ++u) { mx = fmaxf(mx, xr[u]); sum += xr[u]; }
            float m2 = __shfl_xor(mx, 1), s2 = __shfl_xor(sum, 1);
            mx = fmaxf(mx, m2); sum += s2;
            m2 = __shfl_xor(mx, 2); s2 = __shfl_xor(sum, 2);
            mx = fmaxf(mx, m2); sum += s2;
            if ((t & 3) == 0) {
                int f = t >> 3, gg = (t >> 2) & 1;
                sm.sn.zs[f * 4 + gg]     = mx;
                sm.sn.zs[f * 4 + 2 + gg] = sum * (1.f / 32.f);
            }
        }
        __syncthreads();

        // MLP1: 8 chunks x 16 k, 32 outputs; partials in LDS
        {
            int c = t & 31, chunk = t >> 5;
            int k0 = chunk * 16;
            float acc = 0.f;
#pragma unroll
            for (int kk = 0; kk < 16; ++kk)
                acc += sm.sn.zs[k0 + kk] * W1[(k0 + kk) * 32 + c];
            sm.sn.mlpred[chunk][c] = acc;
        }
        __syncthreads();
        if (t < 32) {
            float acc = b1[t];
#pragma unroll
            for (int ch = 0; ch < 8; ++ch) acc += sm.sn.mlpred[ch][t];
            sm.sn.a1s[t] = fmaxf(acc, 0.f);
        }
        __syncthreads();

        // MLP2: weights[e] for this thread's 8 e-values
        float acc[8];
#pragma unroll
        for (int u = 0; u < 8; ++u) acc[u] = 0.f;
        for (int k = 0; k < 32; ++k) {
            float a = sm.sn.a1s[k];
            float4 w0 = *reinterpret_cast<const float4*>(W2 + (size_t)k * EMB + e0);
            float4 w1 = *reinterpret_cast<const float4*>(W2 + (size_t)k * EMB + e0 + 4);
            acc[0] += a * w0.x; acc[1] += a * w0.y; acc[2] += a * w0.z; acc[3] += a * w0.w;
            acc[4] += a * w1.x; acc[5] += a * w1.y; acc[6] += a * w1.z; acc[7] += a * w1.w;
        }
        float4 b2v0 = *reinterpret_cast<const float4*>(b2 + e0);
        float4 b2v1 = *reinterpret_cast<const float4*>(b2 + e0 + 4);
        float b2a[8] = {b2v0.x, b2v0.y, b2v0.z, b2v0.w, b2v1.x, b2v1.y, b2v1.z, b2v1.w};

        float ssum = 0.f, ssq = 0.f;
#pragma unroll
        for (int u = 0; u < 8; ++u) {
            float s = xr[u] * (acc[u] + b2a[u] + 1.0f);
            xr[u] = s;
            ssum += s; ssq += s * s;
        }
        int lane = t & 63, wv = t >> 6;
        for (int off = 32; off; off >>= 1) {
            ssum += __shfl_down(ssum, off);
            ssq  += __shfl_down(ssq, off);
        }
        if (lane == 0) { sm.sn.red[0][wv] = ssum; sm.sn.red[1][wv] = ssq; }
        __syncthreads();
        float a = 0.f, q = 0.f;
#pragma unroll
        for (int i = 0; i < 4; ++i) { a += sm.sn.red[0][i]; q += sm.sn.red[1][i]; }
        float mu = a * (1.f / 2048.f);
        float var = q * (1.f / 2048.f) - mu * mu;
        float rs = rsqrtf(var + LN_EPS);

        float4 lsv0 = *reinterpret_cast<const float4*>(ln_s + e0);
        float4 lsv1 = *reinterpret_cast<const float4*>(ln_s + e0 + 4);
        float4 lbv0 = *reinterpret_cast<const float4*>(ln_b + e0);
        float4 lbv1 = *reinterpret_cast<const float4*>(ln_b + e0 + 4);
        float* orow = out + (size_t)b * OUT_STRIDE + e0;
        float4 o0, o1;
        o0.x = (xr[0] - mu) * rs * lsv0.x + lbv0.x;
        o0.y = (xr[1] - mu) * rs * lsv0.y + lbv0.y;
        o0.z = (xr[2] - mu) * rs * lsv0.z + lbv0.z;
        o0.w = (xr[3] - mu) * rs * lsv0.w + lbv0.w;
        o1.x = (xr[4] - mu) * rs * lsv1.x + lbv1.x;
        o1.y = (xr[5] - mu) * rs * lsv1.y + lbv1.y;
        o1.z = (xr[6] - mu) * rs * lsv1.z + lbv1.z;
        o1.w = (xr[7] - mu) * rs * lsv1.w + lbv1.w;
        *reinterpret_cast<float4*>(orow)     = o0;
        *reinterpret_cast<float4*>(orow + 4) = o1;
    } else if (blk < 1520) {                // ---- cvt+transpose Wp ----
        int p = blk - 1024;
        const float* src = Wp + (size_t)p * 4096;
        ushort* dst = Wpt + (size_t)p * 4096;
#pragma unroll
        for (int it = 0; it < 4; ++it) {
            int d = it * 16 + (t >> 4);
            int e4 = (t & 15) * 4;
            float4 v = *reinterpret_cast<const float4*>(src + d * 64 + e4);
            sm.tile[d][e4] = v.x; sm.tile[d][e4 + 1] = v.y;
            sm.tile[d][e4 + 2] = v.z; sm.tile[d][e4 + 3] = v.w;
        }
        __syncthreads();
#pragma unroll
        for (int it = 0; it < 4; ++it) {
            int e = it * 16 + (t >> 4);
            int d4 = (t & 15) * 4;
            ushort4 o;
            o.x = f2bf(sm.tile[d4][e]);     o.y = f2bf(sm.tile[d4 + 1][e]);
            o.z = f2bf(sm.tile[d4 + 2][e]); o.w = f2bf(sm.tile[d4 + 3][e]);
            *reinterpret_cast<ushort4*>(dst + e * 64 + d4) = o;
        }
    } else if (blk < 1584) {                // ---- cvt+transpose Wo ----
        int bidx = blk - 1520;
        int k0 = (bidx & 7) * 64;
        int n0 = (bidx >> 3) * 64;
#pragma unroll
        for (int it = 0; it < 4; ++it) {
            int kr = it * 16 + (t >> 4);
            int nc = (t & 15) * 4;
            int k = k0 + kr;
            float4 v = {0.f, 0.f, 0.f, 0.f};
            if (k < P_PAIRS) v = *reinterpret_cast<const float4*>(Wo + (size_t)k * OUT_N + n0 + nc);
            sm.tile[kr][nc] = v.x; sm.tile[kr][nc + 1] = v.y;
            sm.tile[kr][nc + 2] = v.z; sm.tile[kr][nc + 3] = v.w;
        }
        __syncthreads();
#pragma unroll
        for (int it = 0; it < 4; ++it) {
            int nr = it * 16 + (t >> 4);
            int kc = (t & 15) * 4;
            ushort4 o;
            o.x = f2bf(sm.tile[kc][nr]);     o.y = f2bf(sm.tile[kc + 1][nr]);
            o.z = f2bf(sm.tile[kc + 2][nr]); o.w = f2bf(sm.tile[kc + 3][nr]);
            *reinterpret_cast<ushort4*>(Wot + (size_t)(n0 + nr) * KPAD + k0 + kc) = o;
        }
    } else {                                // ---- zero db pad cols ----
        int tid = (blk - 1584) * 256 + t;
        if (tid < B_SZ) {
            bf16x8 z = {0, 0, 0, 0, 0, 0, 0, 0};
            ushort* dstp = db + (size_t)tid * KPAD + P_PAIRS;
            *reinterpret_cast<bf16x8*>(dstp) = z;
            *reinterpret_cast<bf16x8*>(dstp + 8) = z;
        }
    }
}

// ---------- pair bilinear: quarter-batch + 2-deep prefetch (R13 verbatim) ----
__global__ __launch_bounds__(256) void k_dots(
        const ushort* __restrict__ xb, const ushort* __restrict__ Wpt,
        const float* __restrict__ bp, ushort* __restrict__ db) {
    int p = blockIdx.x >> 2;
    int q = blockIdx.x & 3;
    int i = 0, rem = p;
    while (rem >= F_FEAT - 1 - i) { rem -= F_FEAT - 1 - i; ++i; }
    int j = i + 1 + rem;

    int wave = threadIdx.x >> 6, lane = threadIdx.x & 63;
    int row = lane & 15, kg = lane >> 4;

    bf16x8 wfr[4][2];
#pragma unroll
    for (int nt = 0; nt < 4; ++nt)
#pragma unroll
        for (int ks = 0; ks < 2; ++ks)
            wfr[nt][ks] = *reinterpret_cast<const bf16x8*>(
                Wpt + (size_t)p * 4096 + (nt * 16 + row) * 64 + ks * 32 + kg * 8);

    f32x4 bb[4];
#pragma unroll
    for (int nt = 0; nt < 4; ++nt)
        bb[nt] = *reinterpret_cast<const f32x4*>(bp + p * 64 + nt * 16 + kg * 4);

    const ushort* xi_base = xb + (size_t)row * EMB + i * 64 + kg * 8;
    const ushort* xj_base = xb + (size_t)row * EMB + j * 64 + kg * 4;

    bf16x8 xifr[2][2];
    ushort4 xjw[2][4];

    auto loadit = [&](int it, int buf) {
        size_t boff = (size_t)(q * 256 + (wave * 4 + it) * 16) * EMB;
#pragma unroll
        for (int ks = 0; ks < 2; ++ks)
            xifr[buf][ks] = *reinterpret_cast<const bf16x8*>(xi_base + boff + ks * 32);
#pragma unroll
        for (int nt = 0; nt < 4; ++nt)
            xjw[buf][nt] = *reinterpret_cast<const ushort4*>(xj_base + boff + nt * 16);
    };

    loadit(0, 0);
#pragma unroll
    for (int it = 0; it < 4; ++it) {
        int cur = it & 1;
        if (it < 3) loadit(it + 1, cur ^ 1);

        f32x4 acc[4];
#pragma unroll
        for (int nt = 0; nt < 4; ++nt) {
            acc[nt] = bb[nt];
            acc[nt] = __builtin_amdgcn_mfma_f32_16x16x32_bf16(wfr[nt][0], xifr[cur][0], acc[nt], 0, 0, 0);
            acc[nt] = __builtin_amdgcn_mfma_f32_16x16x32_bf16(wfr[nt][1], xifr[cur][1], acc[nt], 0, 0, 0);
        }

        float v = 0.f;
#pragma unroll
        for (int nt = 0; nt < 4; ++nt) {
            v += acc[nt][0] * bf2f(xjw[cur][nt].x);
            v += acc[nt][1] * bf2f(xjw[cur][nt].y);
            v += acc[nt][2] * bf2f(xjw[cur][nt].z);
            v += acc[nt][3] * bf2f(xjw[cur][nt].w);
        }
        v += __shfl_xor(v, 16);
        v += __shfl_xor(v, 32);
        if (lane < 16) {
            int b0 = q * 256 + (wave * 4 + it) * 16;
            db[(size_t)(b0 + lane) * KPAD + p] = f2bf(v);
        }
    }
}

// ---------- bilinear head (R13 verbatim): 512 blocks, dual k-chain ----------
__global__ __launch_bounds__(256) void k_bilin2(
        const ushort* __restrict__ db, const ushort* __restrict__ Wot,
        const float* __restrict__ bo, float* __restrict__ out) {
    int mt  = blockIdx.x >> 4;
    int nt0 = blockIdx.x & 15;
    int wave = threadIdx.x >> 6, lane = threadIdx.x & 63;
    int wm = wave & 1, wn = wave >> 1;
    int row = lane & 15, kg = lane >> 4;
    int m0 = mt * 32 + wm * 16;
    int n0 = nt0 * 32 + wn * 16;

    f32x4 acc0 = {0.f, 0.f, 0.f, 0.f};
    f32x4 acc1 = {0.f, 0.f, 0.f, 0.f};
    const ushort* arow = db  + (size_t)(m0 + row) * KPAD + kg * 8;
    const ushort* brow = Wot + (size_t)(n0 + row) * KPAD + kg * 8;
#pragma unroll
    for (int ks = 0; ks < 16; ks += 2) {
        bf16x8 a0 = *reinterpret_cast<const bf16x8*>(arow + ks * 32);
        bf16x8 b0 = *reinterpret_cast<const bf16x8*>(brow + ks * 32);
        bf16x8 a1 = *reinterpret_cast<const bf16x8*>(arow + (ks + 1) * 32);
        bf16x8 b1 = *reinterpret_cast<const bf16x8*>(brow + (ks + 1) * 32);
        acc0 = __builtin_amdgcn_mfma_f32_16x16x32_bf16(a0, b0, acc0, 0, 0, 0);
        acc1 = __builtin_amdgcn_mfma_f32_16x16x32_bf16(a1, b1, acc1, 0, 0, 0);
    }
    int col = row;
    float bov = bo[n0 + col];
#pragma unroll
    for (int r = 0; r < 4; ++r) {
        size_t orow = (size_t)(m0 + kg * 4 + r) * OUT_STRIDE + 2048 + n0;
        out[orow + col] = acc0[r] + acc1[r] + bov;
    }
}

extern "C" void kernel_launch(void* const* d_in, const int* in_sizes, int n_in,
                              void* d_out, int out_size, void* d_ws, size_t ws_size,
                              hipStream_t stream) {
    const float* x    = (const float*)d_in[0];
    const float* W1   = (const float*)d_in[1];
    const float* b1   = (const float*)d_in[2];
    const float* W2   = (const float*)d_in[3];
    const float* b2   = (const float*)d_in[4];
    const float* ln_s = (const float*)d_in[5];
    const float* ln_b = (const float*)d_in[6];
    const float* Wp   = (const float*)d_in[7];
    const float* bp   = (const float*)d_in[8];
    const float* Wo   = (const float*)d_in[9];
    const float* bo   = (const float*)d_in[10];
    float* out = (float*)d_out;

    // workspace layout
    ushort* xb   = (ushort*)d_ws;                                        // 4,194,304 B
    ushort* wpt  = (ushort*)((char*)d_ws + 4194304);                     // 4,063,232 B
    ushort* db   = (ushort*)((char*)d_ws + 4194304 + 4063232);           // 1,048,576 B
    ushort* wot  = (ushort*)((char*)d_ws + 4194304 + 4063232 + 1048576); //   524,288 B

    k_front<<<1592, 256, 0, stream>>>(x, xb, W1, b1, W2, b2, ln_s, ln_b,
                                      Wp, wpt, Wo, wot, db, out);
    k_dots<<<P_PAIRS * 4, 256, 0, stream>>>(xb, wpt, bp, db);
    k_bilin2<<<512, 256, 0, stream>>>(db, wot, bo, out);
}

// Round 17
// 67.308 us; speedup vs baseline: 1.0043x; 1.0043x over previous
//
#include <hip/hip_runtime.h>
#include <hip/hip_bf16.h>

#define F_FEAT 32
#define D_DIM 64
#define B_SZ 1024
#define EMB 2048
#define P_PAIRS 496
#define KPAD 512
#define OUT_N 512
#define OUT_STRIDE 2560
#define LN_EPS 1e-6f

typedef __attribute__((ext_vector_type(8))) short bf16x8;
typedef __attribute__((ext_vector_type(4))) float f32x4;

__device__ inline ushort f2bf(float f) {
    union { float f; unsigned u; } a; a.f = f;
    unsigned u = a.u;
    unsigned r = (u + 0x7FFFu + ((u >> 16) & 1u)) >> 16;   // RTNE
    return (ushort)r;
}
__device__ inline float bf2f(ushort u) {
    union { unsigned u; float f; } a; a.u = ((unsigned)u) << 16;
    return a.f;
}

// ---------- front (256 thr): senet 1-row/block | Wp | Wo | db pad ----------
// blocks [0,1024)      : SENet+LN, one batch row per block, register-resident
// blocks [1024,1520)   : Wp[p][d][e] -> Wpt[p][e][d] bf16 (R2-proven)
// blocks [1520,1584)   : Wo[k][n] -> Wot[n][k] bf16, k padded (R2-proven)
// blocks [1584,1592)   : zero db[:, 496:512]
__global__ __launch_bounds__(256) void k_front(
        const float* __restrict__ x, ushort* __restrict__ xb,
        const float* __restrict__ W1, const float* __restrict__ b1,
        const float* __restrict__ W2, const float* __restrict__ b2,
        const float* __restrict__ ln_s, const float* __restrict__ ln_b,
        const float* __restrict__ Wp, ushort* __restrict__ Wpt,
        const float* __restrict__ Wo, ushort* __restrict__ Wot,
        ushort* __restrict__ db, float* __restrict__ out) {
    __shared__ union {
        float tile[64][65];
        struct {
            float zs[128];
            float a1s[32];
            float mlpred[8][32];
            float red[2][4];
        } sn;
    } sm;
    int t = threadIdx.x;
    int blk = blockIdx.x;

    if (blk < 1024) {
        // ================ SENet, 1 row, register-resident ================
        int b = blk;
        int e0 = t * 8;
        const float* xrow = x + (size_t)b * EMB + e0;
        float4 v0 = *reinterpret_cast<const float4*>(xrow);
        float4 v1 = *reinterpret_cast<const float4*>(xrow + 4);
        float xr[8] = {v0.x, v0.y, v0.z, v0.w, v1.x, v1.y, v1.z, v1.w};

        // emit xb (16B per thread, coalesced)
        bf16x8 ob;
#pragma unroll
        for (int u = 0; u < 8; ++u) ob[u] = (short)f2bf(xr[u]);
        *reinterpret_cast<bf16x8*>(xb + (size_t)b * EMB + e0) = ob;

        // squeeze: thread owns 1/4 of one (f,gg) 32-elem window
        {
            float mx = xr[0], sum = xr[0];
#pragma unroll
            for (int u = 1; u < 8; ++u) { mx = fmaxf(mx, xr[u]); sum += xr[u]; }
            float m2 = __shfl_xor(mx, 1), s2 = __shfl_xor(sum, 1);
            mx = fmaxf(mx, m2); sum += s2;
            m2 = __shfl_xor(mx, 2); s2 = __shfl_xor(sum, 2);
            mx = fmaxf(mx, m2); sum += s2;
            if ((t & 3) == 0) {
                int f = t >> 3, gg = (t >> 2) & 1;
                sm.sn.zs[f * 4 + gg]     = mx;
                sm.sn.zs[f * 4 + 2 + gg] = sum * (1.f / 32.f);
            }
        }
        __syncthreads();

        // MLP1: 8 chunks x 16 k, 32 outputs; partials in LDS
        {
            int c = t & 31, chunk = t >> 5;
            int k0 = chunk * 16;
            float acc = 0.f;
#pragma unroll
            for (int kk = 0; kk < 16; ++kk)
                acc += sm.sn.zs[k0 + kk] * W1[(k0 + kk) * 32 + c];
            sm.sn.mlpred[chunk][c] = acc;
        }
        __syncthreads();
        if (t < 32) {
            float acc = b1[t];
#pragma unroll
            for (int ch = 0; ch < 8; ++ch) acc += sm.sn.mlpred[ch][t];
            sm.sn.a1s[t] = fmaxf(acc, 0.f);
        }
        __syncthreads();

        // MLP2: weights[e] for this thread's 8 e-values
        float acc[8];
#pragma unroll
        for (int u = 0; u < 8; ++u) acc[u] = 0.f;
        for (int k = 0; k < 32; ++k) {
            float a = sm.sn.a1s[k];
            float4 w0 = *reinterpret_cast<const float4*>(W2 + (size_t)k * EMB + e0);
            float4 w1 = *reinterpret_cast<const float4*>(W2 + (size_t)k * EMB + e0 + 4);
            acc[0] += a * w0.x; acc[1] += a * w0.y; acc[2] += a * w0.z; acc[3] += a * w0.w;
            acc[4] += a * w1.x; acc[5] += a * w1.y; acc[6] += a * w1.z; acc[7] += a * w1.w;
        }
        float4 b2v0 = *reinterpret_cast<const float4*>(b2 + e0);
        float4 b2v1 = *reinterpret_cast<const float4*>(b2 + e0 + 4);
        float b2a[8] = {b2v0.x, b2v0.y, b2v0.z, b2v0.w, b2v1.x, b2v1.y, b2v1.z, b2v1.w};

        float ssum = 0.f, ssq = 0.f;
#pragma unroll
        for (int u = 0; u < 8; ++u) {
            float s = xr[u] * (acc[u] + b2a[u] + 1.0f);
            xr[u] = s;
            ssum += s; ssq += s * s;
        }
        int lane = t & 63, wv = t >> 6;
        for (int off = 32; off; off >>= 1) {
            ssum += __shfl_down(ssum, off);
            ssq  += __shfl_down(ssq, off);
        }
        if (lane == 0) { sm.sn.red[0][wv] = ssum; sm.sn.red[1][wv] = ssq; }
        __syncthreads();
        float a = 0.f, q = 0.f;
#pragma unroll
        for (int i = 0; i < 4; ++i) { a += sm.sn.red[0][i]; q += sm.sn.red[1][i]; }
        float mu = a * (1.f / 2048.f);
        float var = q * (1.f / 2048.f) - mu * mu;
        float rs = rsqrtf(var + LN_EPS);

        float4 lsv0 = *reinterpret_cast<const float4*>(ln_s + e0);
        float4 lsv1 = *reinterpret_cast<const float4*>(ln_s + e0 + 4);
        float4 lbv0 = *reinterpret_cast<const float4*>(ln_b + e0);
        float4 lbv1 = *reinterpret_cast<const float4*>(ln_b + e0 + 4);
        float* orow = out + (size_t)b * OUT_STRIDE + e0;
        float4 o0, o1;
        o0.x = (xr[0] - mu) * rs * lsv0.x + lbv0.x;
        o0.y = (xr[1] - mu) * rs * lsv0.y + lbv0.y;
        o0.z = (xr[2] - mu) * rs * lsv0.z + lbv0.z;
        o0.w = (xr[3] - mu) * rs * lsv0.w + lbv0.w;
        o1.x = (xr[4] - mu) * rs * lsv1.x + lbv1.x;
        o1.y = (xr[5] - mu) * rs * lsv1.y + lbv1.y;
        o1.z = (xr[6] - mu) * rs * lsv1.z + lbv1.z;
        o1.w = (xr[7] - mu) * rs * lsv1.w + lbv1.w;
        *reinterpret_cast<float4*>(orow)     = o0;
        *reinterpret_cast<float4*>(orow + 4) = o1;
    } else if (blk < 1520) {                // ---- cvt+transpose Wp ----
        int p = blk - 1024;
        const float* src = Wp + (size_t)p * 4096;
        ushort* dst = Wpt + (size_t)p * 4096;
#pragma unroll
        for (int it = 0; it < 4; ++it) {
            int d = it * 16 + (t >> 4);
            int e4 = (t & 15) * 4;
            float4 v = *reinterpret_cast<const float4*>(src + d * 64 + e4);
            sm.tile[d][e4] = v.x; sm.tile[d][e4 + 1] = v.y;
            sm.tile[d][e4 + 2] = v.z; sm.tile[d][e4 + 3] = v.w;
        }
        __syncthreads();
#pragma unroll
        for (int it = 0; it < 4; ++it) {
            int e = it * 16 + (t >> 4);
            int d4 = (t & 15) * 4;
            ushort4 o;
            o.x = f2bf(sm.tile[d4][e]);     o.y = f2bf(sm.tile[d4 + 1][e]);
            o.z = f2bf(sm.tile[d4 + 2][e]); o.w = f2bf(sm.tile[d4 + 3][e]);
            *reinterpret_cast<ushort4*>(dst + e * 64 + d4) = o;
        }
    } else if (blk < 1584) {                // ---- cvt+transpose Wo ----
        int bidx = blk - 1520;
        int k0 = (bidx & 7) * 64;
        int n0 = (bidx >> 3) * 64;
#pragma unroll
        for (int it = 0; it < 4; ++it) {
            int kr = it * 16 + (t >> 4);
            int nc = (t & 15) * 4;
            int k = k0 + kr;
            float4 v = {0.f, 0.f, 0.f, 0.f};
            if (k < P_PAIRS) v = *reinterpret_cast<const float4*>(Wo + (size_t)k * OUT_N + n0 + nc);
            sm.tile[kr][nc] = v.x; sm.tile[kr][nc + 1] = v.y;
            sm.tile[kr][nc + 2] = v.z; sm.tile[kr][nc + 3] = v.w;
        }
        __syncthreads();
#pragma unroll
        for (int it = 0; it < 4; ++it) {
            int nr = it * 16 + (t >> 4);
            int kc = (t & 15) * 4;
            ushort4 o;
            o.x = f2bf(sm.tile[kc][nr]);     o.y = f2bf(sm.tile[kc + 1][nr]);
            o.z = f2bf(sm.tile[kc + 2][nr]); o.w = f2bf(sm.tile[kc + 3][nr]);
            *reinterpret_cast<ushort4*>(Wot + (size_t)(n0 + nr) * KPAD + k0 + kc) = o;
        }
    } else {                                // ---- zero db pad cols ----
        int tid = (blk - 1584) * 256 + t;
        if (tid < B_SZ) {
            bf16x8 z = {0, 0, 0, 0, 0, 0, 0, 0};
            ushort* dstp = db + (size_t)tid * KPAD + P_PAIRS;
            *reinterpret_cast<bf16x8*>(dstp) = z;
            *reinterpret_cast<bf16x8*>(dstp + 8) = z;
        }
    }
}

// ---------- pair bilinear: quarter-batch + 2-deep prefetch (R13 verbatim) ----
__global__ __launch_bounds__(256) void k_dots(
        const ushort* __restrict__ xb, const ushort* __restrict__ Wpt,
        const float* __restrict__ bp, ushort* __restrict__ db) {
    int p = blockIdx.x >> 2;
    int q = blockIdx.x & 3;
    int i = 0, rem = p;
    while (rem >= F_FEAT - 1 - i) { rem -= F_FEAT - 1 - i; ++i; }
    int j = i + 1 + rem;

    int wave = threadIdx.x >> 6, lane = threadIdx.x & 63;
    int row = lane & 15, kg = lane >> 4;

    bf16x8 wfr[4][2];
#pragma unroll
    for (int nt = 0; nt < 4; ++nt)
#pragma unroll
        for (int ks = 0; ks < 2; ++ks)
            wfr[nt][ks] = *reinterpret_cast<const bf16x8*>(
                Wpt + (size_t)p * 4096 + (nt * 16 + row) * 64 + ks * 32 + kg * 8);

    f32x4 bb[4];
#pragma unroll
    for (int nt = 0; nt < 4; ++nt)
        bb[nt] = *reinterpret_cast<const f32x4*>(bp + p * 64 + nt * 16 + kg * 4);

    const ushort* xi_base = xb + (size_t)row * EMB + i * 64 + kg * 8;
    const ushort* xj_base = xb + (size_t)row * EMB + j * 64 + kg * 4;

    bf16x8 xifr[2][2];
    ushort4 xjw[2][4];

    auto loadit = [&](int it, int buf) {
        size_t boff = (size_t)(q * 256 + (wave * 4 + it) * 16) * EMB;
#pragma unroll
        for (int ks = 0; ks < 2; ++ks)
            xifr[buf][ks] = *reinterpret_cast<const bf16x8*>(xi_base + boff + ks * 32);
#pragma unroll
        for (int nt = 0; nt < 4; ++nt)
            xjw[buf][nt] = *reinterpret_cast<const ushort4*>(xj_base + boff + nt * 16);
    };

    loadit(0, 0);
#pragma unroll
    for (int it = 0; it < 4; ++it) {
        int cur = it & 1;
        if (it < 3) loadit(it + 1, cur ^ 1);

        f32x4 acc[4];
#pragma unroll
        for (int nt = 0; nt < 4; ++nt) {
            acc[nt] = bb[nt];
            acc[nt] = __builtin_amdgcn_mfma_f32_16x16x32_bf16(wfr[nt][0], xifr[cur][0], acc[nt], 0, 0, 0);
            acc[nt] = __builtin_amdgcn_mfma_f32_16x16x32_bf16(wfr[nt][1], xifr[cur][1], acc[nt], 0, 0, 0);
        }

        float v = 0.f;
#pragma unroll
        for (int nt = 0; nt < 4; ++nt) {
            v += acc[nt][0] * bf2f(xjw[cur][nt].x);
            v += acc[nt][1] * bf2f(xjw[cur][nt].y);
            v += acc[nt][2] * bf2f(xjw[cur][nt].z);
            v += acc[nt][3] * bf2f(xjw[cur][nt].w);
        }
        v += __shfl_xor(v, 16);
        v += __shfl_xor(v, 32);
        if (lane < 16) {
            int b0 = q * 256 + (wave * 4 + it) * 16;
            db[(size_t)(b0 + lane) * KPAD + p] = f2bf(v);
        }
    }
}

// ---------- bilinear head (R13 verbatim): 512 blocks, dual k-chain ----------
__global__ __launch_bounds__(256) void k_bilin2(
        const ushort* __restrict__ db, const ushort* __restrict__ Wot,
        const float* __restrict__ bo, float* __restrict__ out) {
    int mt  = blockIdx.x >> 4;
    int nt0 = blockIdx.x & 15;
    int wave = threadIdx.x >> 6, lane = threadIdx.x & 63;
    int wm = wave & 1, wn = wave >> 1;
    int row = lane & 15, kg = lane >> 4;
    int m0 = mt * 32 + wm * 16;
    int n0 = nt0 * 32 + wn * 16;

    f32x4 acc0 = {0.f, 0.f, 0.f, 0.f};
    f32x4 acc1 = {0.f, 0.f, 0.f, 0.f};
    const ushort* arow = db  + (size_t)(m0 + row) * KPAD + kg * 8;
    const ushort* brow = Wot + (size_t)(n0 + row) * KPAD + kg * 8;
#pragma unroll
    for (int ks = 0; ks < 16; ks += 2) {
        bf16x8 a0 = *reinterpret_cast<const bf16x8*>(arow + ks * 32);
        bf16x8 b0 = *reinterpret_cast<const bf16x8*>(brow + ks * 32);
        bf16x8 a1 = *reinterpret_cast<const bf16x8*>(arow + (ks + 1) * 32);
        bf16x8 b1 = *reinterpret_cast<const bf16x8*>(brow + (ks + 1) * 32);
        acc0 = __builtin_amdgcn_mfma_f32_16x16x32_bf16(a0, b0, acc0, 0, 0, 0);
        acc1 = __builtin_amdgcn_mfma_f32_16x16x32_bf16(a1, b1, acc1, 0, 0, 0);
    }
    int col = row;
    float bov = bo[n0 + col];
#pragma unroll
    for (int r = 0; r < 4; ++r) {
        size_t orow = (size_t)(m0 + kg * 4 + r) * OUT_STRIDE + 2048 + n0;
        out[orow + col] = acc0[r] + acc1[r] + bov;
    }
}

extern "C" void kernel_launch(void* const* d_in, const int* in_sizes, int n_in,
                              void* d_out, int out_size, void* d_ws, size_t ws_size,
                              hipStream_t stream) {
    const float* x    = (const float*)d_in[0];
    const float* W1   = (const float*)d_in[1];
    const float* b1   = (const float*)d_in[2];
    const float* W2   = (const float*)d_in[3];
    const float* b2   = (const float*)d_in[4];
    const float* ln_s = (const float*)d_in[5];
    const float* ln_b = (const float*)d_in[6];
    const float* Wp   = (const float*)d_in[7];
    const float* bp   = (const float*)d_in[8];
    const float* Wo   = (const float*)d_in[9];
    const float* bo   = (const float*)d_in[10];
    float* out = (float*)d_out;

    // workspace layout
    ushort* xb   = (ushort*)d_ws;                                        // 4,194,304 B
    ushort* wpt  = (ushort*)((char*)d_ws + 4194304);                     // 4,063,232 B
    ushort* db   = (ushort*)((char*)d_ws + 4194304 + 4063232);           // 1,048,576 B
    ushort* wot  = (ushort*)((char*)d_ws + 4194304 + 4063232 + 1048576); //   524,288 B

    k_front<<<1592, 256, 0, stream>>>(x, xb, W1, b1, W2, b2, ln_s, ln_b,
                                      Wp, wpt, Wo, wot, db, out);
    k_dots<<<P_PAIRS * 4, 256, 0, stream>>>(xb, wpt, bp, db);
    k_bilin2<<<512, 256, 0, stream>>>(db, wot, bo, out);
}

// Round 18
// 57.275 us; speedup vs baseline: 1.1802x; 1.1752x over previous
//
#include <hip/hip_runtime.h>
#include <hip/hip_bf16.h>

#define F_FEAT 32
#define D_DIM 64
#define B_SZ 1024
#define EMB 2048
#define P_PAIRS 496
#define KPAD 512
#define OUT_N 512
#define OUT_STRIDE 2560
#define LN_EPS 1e-6f

typedef __attribute__((ext_vector_type(8))) short bf16x8;
typedef __attribute__((ext_vector_type(4))) float f32x4;

__device__ inline ushort f2bf(float f) {
    union { float f; unsigned u; } a; a.f = f;
    unsigned u = a.u;
    unsigned r = (u + 0x7FFFu + ((u >> 16) & 1u)) >> 16;   // RTNE
    return (ushort)r;
}
__device__ inline float bf2f(ushort u) {
    union { unsigned u; float f; } a; a.u = ((unsigned)u) << 16;
    return a.f;
}

// ---------- prep: cvt+transpose Wp | cvt+transpose Wo | zero db pad ----------
__global__ __launch_bounds__(256) void k_prep(
        const float* __restrict__ Wp, ushort* __restrict__ Wpt,
        const float* __restrict__ Wo, ushort* __restrict__ Wot,
        ushort* __restrict__ db) {
    __shared__ float tile[64][65];
    int t = threadIdx.x;
    int blk = blockIdx.x;

    if (blk < 496) {                        // ---- cvt+transpose Wp ----
        int p = blk;
        const float* src = Wp + (size_t)p * 4096;
        ushort* dst = Wpt + (size_t)p * 4096;
#pragma unroll
        for (int it = 0; it < 4; ++it) {
            int d = it * 16 + (t >> 4);
            int e4 = (t & 15) * 4;
            float4 v = *reinterpret_cast<const float4*>(src + d * 64 + e4);
            tile[d][e4] = v.x; tile[d][e4 + 1] = v.y; tile[d][e4 + 2] = v.z; tile[d][e4 + 3] = v.w;
        }
        __syncthreads();
#pragma unroll
        for (int it = 0; it < 4; ++it) {
            int e = it * 16 + (t >> 4);
            int d4 = (t & 15) * 4;
            ushort4 o;
            o.x = f2bf(tile[d4][e]);     o.y = f2bf(tile[d4 + 1][e]);
            o.z = f2bf(tile[d4 + 2][e]); o.w = f2bf(tile[d4 + 3][e]);
            *reinterpret_cast<ushort4*>(dst + e * 64 + d4) = o;
        }
    } else if (blk < 560) {                 // ---- cvt+transpose Wo ----
        int bidx = blk - 496;
        int k0 = (bidx & 7) * 64;
        int n0 = (bidx >> 3) * 64;
#pragma unroll
        for (int it = 0; it < 4; ++it) {
            int kr = it * 16 + (t >> 4);
            int nc = (t & 15) * 4;
            int k = k0 + kr;
            float4 v = {0.f, 0.f, 0.f, 0.f};
            if (k < P_PAIRS) v = *reinterpret_cast<const float4*>(Wo + (size_t)k * OUT_N + n0 + nc);
            tile[kr][nc] = v.x; tile[kr][nc + 1] = v.y; tile[kr][nc + 2] = v.z; tile[kr][nc + 3] = v.w;
        }
        __syncthreads();
#pragma unroll
        for (int it = 0; it < 4; ++it) {
            int nr = it * 16 + (t >> 4);
            int kc = (t & 15) * 4;
            ushort4 o;
            o.x = f2bf(tile[kc][nr]);     o.y = f2bf(tile[kc + 1][nr]);
            o.z = f2bf(tile[kc + 2][nr]); o.w = f2bf(tile[kc + 3][nr]);
            *reinterpret_cast<ushort4*>(Wot + (size_t)(n0 + nr) * KPAD + k0 + kc) = o;
        }
    } else {                                // ---- zero db pad cols ----
        int tid = (blk - 560) * 256 + t;
        if (tid < B_SZ) {
            bf16x8 z = {0, 0, 0, 0, 0, 0, 0, 0};
            ushort* dstp = db + (size_t)tid * KPAD + P_PAIRS;
            *reinterpret_cast<bf16x8*>(dstp) = z;
            *reinterpret_cast<bf16x8*>(dstp + 8) = z;
        }
    }
}

// ---------- SENet branch (R9-proven: LDS-staged x, parallel squeeze/MLP) ----
// 4 rows/block amortizes W2 reads 4x (1-row variant quadruples L2 traffic: R17).
__global__ __launch_bounds__(512) void k_senet(
        const float* __restrict__ x, ushort* __restrict__ xb,
        const float* __restrict__ W1, const float* __restrict__ b1,
        const float* __restrict__ W2, const float* __restrict__ b2,
        const float* __restrict__ ln_s, const float* __restrict__ ln_b,
        float* __restrict__ out) {
    __shared__ float xs[4][EMB];
    __shared__ float zs[4][128];
    __shared__ float a1s[4][32];
    __shared__ float red[2][4][8];
    __shared__ float mlpred[2][128];
    int t = threadIdx.x;
    int b0 = blockIdx.x * 4;

    for (int r = 0; r < 4; ++r) {
        const float4* src = reinterpret_cast<const float4*>(x + (size_t)(b0 + r) * EMB);
        float4 v = src[t];
        reinterpret_cast<float4*>(&xs[r][0])[t] = v;
        ushort4 o;
        o.x = f2bf(v.x); o.y = f2bf(v.y); o.z = f2bf(v.z); o.w = f2bf(v.w);
        *reinterpret_cast<ushort4*>(xb + (size_t)(b0 + r) * EMB + t * 4) = o;
    }
    __syncthreads();

    // squeeze: all 512 threads; (r,f,gg) group = 32 elems handled by 2 threads x 16
    {
        int g2 = t >> 1, sub = t & 1;
        int r = g2 >> 6, fg = g2 & 63, f = fg >> 1, gg = fg & 1;
        const float* base = &xs[r][f * 64 + gg * 32 + sub * 16];
        float mx = -INFINITY, sm = 0.f;
#pragma unroll
        for (int q = 0; q < 16; ++q) {
            float v = base[(q + t) & 15];      // lane-rotated: ~2-way banks (free)
            mx = fmaxf(mx, v); sm += v;
        }
        float mx2 = __shfl_xor(mx, 1);
        float sm2 = __shfl_xor(sm, 1);
        mx = fmaxf(mx, mx2); sm += sm2;
        if (sub == 0) {
            zs[r][f * 4 + gg]     = mx;
            zs[r][f * 4 + 2 + gg] = sm * (1.f / 32.f);
        }
    }
    __syncthreads();

    // MLP layer1: 256 threads, 2 k-chunks x 64, LDS reduce
    if (t < 256) {
        int chunk = t >> 7, c = t & 127;
        int r = c >> 5, cc = c & 31;
        float acc = 0.f;
        int k0 = chunk * 64;
#pragma unroll
        for (int k = 0; k < 64; ++k) acc += zs[r][k0 + k] * W1[(k0 + k) * 32 + cc];
        mlpred[chunk][c] = acc;
    }
    __syncthreads();
    if (t < 128) {
        int r = t >> 5, cc = t & 31;
        a1s[r][cc] = fmaxf(mlpred[0][t] + mlpred[1][t] + b1[cc], 0.f);
    }
    __syncthreads();

    float acc[4][4];
#pragma unroll
    for (int r = 0; r < 4; ++r)
#pragma unroll
        for (int u = 0; u < 4; ++u) acc[r][u] = 0.f;

    for (int k = 0; k < 32; ++k) {
        float a0 = a1s[0][k], a1v = a1s[1][k], a2 = a1s[2][k], a3 = a1s[3][k];
#pragma unroll
        for (int u = 0; u < 4; ++u) {
            float wv = W2[k * EMB + t + 512 * u];
            acc[0][u] += a0 * wv; acc[1][u] += a1v * wv;
            acc[2][u] += a2 * wv; acc[3][u] += a3 * wv;
        }
    }
    float ssum[4], ssq[4];
#pragma unroll
    for (int r = 0; r < 4; ++r) { ssum[r] = 0.f; ssq[r] = 0.f; }
#pragma unroll
    for (int r = 0; r < 4; ++r) {
#pragma unroll
        for (int u = 0; u < 4; ++u) {
            int e = t + 512 * u;
            float w = acc[r][u] + b2[e];
            float s = xs[r][e] * (w + 1.0f);
            xs[r][e] = s;
            ssum[r] += s; ssq[r] += s * s;
        }
    }
    int lane = t & 63, w = t >> 6;
#pragma unroll
    for (int r = 0; r < 4; ++r) {
        float a = ssum[r], q = ssq[r];
        for (int off = 32; off; off >>= 1) { a += __shfl_down(a, off); q += __shfl_down(q, off); }
        if (lane == 0) { red[0][r][w] = a; red[1][r][w] = q; }
    }
    __syncthreads();
    float mu[4], rs[4];
#pragma unroll
    for (int r = 0; r < 4; ++r) {
        float a = 0.f, q = 0.f;
#pragma unroll
        for (int i = 0; i < 8; ++i) { a += red[0][r][i]; q += red[1][r][i]; }
        mu[r] = a * (1.f / 2048.f);
        float var = q * (1.f / 2048.f) - mu[r] * mu[r];
        rs[r] = rsqrtf(var + LN_EPS);
    }
#pragma unroll
    for (int r = 0; r < 4; ++r) {
#pragma unroll
        for (int u = 0; u < 4; ++u) {
            int e = t + 512 * u;
            float s = xs[r][e];
            out[(size_t)(b0 + r) * OUT_STRIDE + e] = (s - mu[r]) * rs[r] * ln_s[e] + ln_b[e];
        }
    }
}

// ---------- pair bilinear, 2-deep software-pipelined loads (R9-proven) ----------
__global__ __launch_bounds__(256) void k_dots(
        const ushort* __restrict__ xb, const ushort* __restrict__ Wpt,
        const float* __restrict__ bp, ushort* __restrict__ db) {
    int p = blockIdx.x >> 1;
    int h = blockIdx.x & 1;
    int i = 0, rem = p;
    while (rem >= F_FEAT - 1 - i) { rem -= F_FEAT - 1 - i; ++i; }
    int j = i + 1 + rem;

    int wave = threadIdx.x >> 6, lane = threadIdx.x & 63;
    int row = lane & 15, kg = lane >> 4;

    bf16x8 wfr[4][2];
#pragma unroll
    for (int nt = 0; nt < 4; ++nt)
#pragma unroll
        for (int ks = 0; ks < 2; ++ks)
            wfr[nt][ks] = *reinterpret_cast<const bf16x8*>(
                Wpt + (size_t)p * 4096 + (nt * 16 + row) * 64 + ks * 32 + kg * 8);

    f32x4 bb[4];
#pragma unroll
    for (int nt = 0; nt < 4; ++nt)
        bb[nt] = *reinterpret_cast<const f32x4*>(bp + p * 64 + nt * 16 + kg * 4);

    const ushort* xi_base = xb + (size_t)row * EMB + i * 64 + kg * 8;
    const ushort* xj_base = xb + (size_t)row * EMB + j * 64 + kg * 4;

    bf16x8 xifr[2][2];
    ushort4 xjw[2][4];

    auto loadit = [&](int it, int buf) {
        size_t boff = (size_t)(h * 512 + (wave * 8 + it) * 16) * EMB;
#pragma unroll
        for (int ks = 0; ks < 2; ++ks)
            xifr[buf][ks] = *reinterpret_cast<const bf16x8*>(xi_base + boff + ks * 32);
#pragma unroll
        for (int nt = 0; nt < 4; ++nt)
            xjw[buf][nt] = *reinterpret_cast<const ushort4*>(xj_base + boff + nt * 16);
    };

    loadit(0, 0);
#pragma unroll
    for (int it = 0; it < 8; ++it) {
        int cur = it & 1;
        if (it < 7) loadit(it + 1, cur ^ 1);   // prefetch next tile before compute

        f32x4 acc[4];
#pragma unroll
        for (int nt = 0; nt < 4; ++nt) {
            acc[nt] = bb[nt];
            acc[nt] = __builtin_amdgcn_mfma_f32_16x16x32_bf16(wfr[nt][0], xifr[cur][0], acc[nt], 0, 0, 0);
            acc[nt] = __builtin_amdgcn_mfma_f32_16x16x32_bf16(wfr[nt][1], xifr[cur][1], acc[nt], 0, 0, 0);
        }

        float v = 0.f;
#pragma unroll
        for (int nt = 0; nt < 4; ++nt) {
            v += acc[nt][0] * bf2f(xjw[cur][nt].x);
            v += acc[nt][1] * bf2f(xjw[cur][nt].y);
            v += acc[nt][2] * bf2f(xjw[cur][nt].z);
            v += acc[nt][3] * bf2f(xjw[cur][nt].w);
        }
        v += __shfl_xor(v, 16);
        v += __shfl_xor(v, 32);
        if (lane < 16) {
            int b0 = h * 512 + (wave * 8 + it) * 16;
            db[(size_t)(b0 + lane) * KPAD + p] = f2bf(v);
        }
    }
}

// ---------- bilinear head via MFMA: out[:,2048:] = db @ Wot^T + bo ----------
__global__ __launch_bounds__(256) void k_bilin2(
        const ushort* __restrict__ db, const ushort* __restrict__ Wot,
        const float* __restrict__ bo, float* __restrict__ out) {
    int mt  = blockIdx.x >> 4;
    int nt0 = blockIdx.x & 15;
    int wave = threadIdx.x >> 6, lane = threadIdx.x & 63;
    int row = lane & 15, kg = lane >> 4;
    int m0 = mt * 64 + wave * 16;
    int n0 = nt0 * 32;

    f32x4 acc0 = {0.f, 0.f, 0.f, 0.f};
    f32x4 acc1 = {0.f, 0.f, 0.f, 0.f};
    const ushort* arow  = db  + (size_t)(m0 + row) * KPAD + kg * 8;
    const ushort* brow0 = Wot + (size_t)(n0 + row) * KPAD + kg * 8;
    const ushort* brow1 = brow0 + 16 * KPAD;
#pragma unroll
    for (int ks = 0; ks < 16; ++ks) {
        bf16x8 a  = *reinterpret_cast<const bf16x8*>(arow  + ks * 32);
        bf16x8 b0 = *reinterpret_cast<const bf16x8*>(brow0 + ks * 32);
        bf16x8 b1 = *reinterpret_cast<const bf16x8*>(brow1 + ks * 32);
        acc0 = __builtin_amdgcn_mfma_f32_16x16x32_bf16(a, b0, acc0, 0, 0, 0);
        acc1 = __builtin_amdgcn_mfma_f32_16x16x32_bf16(a, b1, acc1, 0, 0, 0);
    }
    int col = row;
    float bo0 = bo[n0 + col], bo1 = bo[n0 + 16 + col];
#pragma unroll
    for (int r = 0; r < 4; ++r) {
        size_t orow = (size_t)(m0 + kg * 4 + r) * OUT_STRIDE + 2048 + n0;
        out[orow + col]      = acc0[r] + bo0;
        out[orow + 16 + col] = acc1[r] + bo1;
    }
}

extern "C" void kernel_launch(void* const* d_in, const int* in_sizes, int n_in,
                              void* d_out, int out_size, void* d_ws, size_t ws_size,
                              hipStream_t stream) {
    const float* x    = (const float*)d_in[0];
    const float* W1   = (const float*)d_in[1];
    const float* b1   = (const float*)d_in[2];
    const float* W2   = (const float*)d_in[3];
    const float* b2   = (const float*)d_in[4];
    const float* ln_s = (const float*)d_in[5];
    const float* ln_b = (const float*)d_in[6];
    const float* Wp   = (const float*)d_in[7];
    const float* bp   = (const float*)d_in[8];
    const float* Wo   = (const float*)d_in[9];
    const float* bo   = (const float*)d_in[10];
    float* out = (float*)d_out;

    // workspace layout
    ushort* xb   = (ushort*)d_ws;                                        // 4,194,304 B
    ushort* wpt  = (ushort*)((char*)d_ws + 4194304);                     // 4,063,232 B
    ushort* db   = (ushort*)((char*)d_ws + 4194304 + 4063232);           // 1,048,576 B
    ushort* wot  = (ushort*)((char*)d_ws + 4194304 + 4063232 + 1048576); //   524,288 B

    k_prep<<<568, 256, 0, stream>>>(Wp, wpt, Wo, wot, db);
    k_senet<<<B_SZ / 4, 512, 0, stream>>>(x, xb, W1, b1, W2, b2, ln_s, ln_b, out);
    k_dots<<<P_PAIRS * 2, 256, 0, stream>>>(xb, wpt, bp, db);
    k_bilin2<<<256, 256, 0, stream>>>(db, wot, bo, out);
}